// Round 7
// baseline (901.218 us; speedup 1.0000x reference)
//
#include <hip/hip_runtime.h>
#include <math.h>

#define BB 32
#define TD 2048
#define TE 1024
#define DIM 256
#define INDIM 80

typedef __attribute__((ext_vector_type(8))) _Float16 f16x8;
typedef __attribute__((ext_vector_type(4))) float f32x4;

__device__ __forceinline__ float sigmoidf_(float x){ return 1.f/(1.f+__expf(-x)); }

// async 16B global->LDS copy (direct DMA, no VGPR round-trip)
__device__ __forceinline__ void cp16(const _Float16* g, _Float16* l){
  __builtin_amdgcn_global_load_lds(
      (const __attribute__((address_space(1))) unsigned int*)g,
      (__attribute__((address_space(3))) unsigned int*)l, 16, 0, 0);
}

// ------- conv weight reorder: w(512,256,5) f32 -> Wf[o][tap*256+ic] fp16 -------
__global__ __launch_bounds__(256) void k_wprep(const float* __restrict__ w,
    _Float16* __restrict__ Wf)
{
  int i = blockIdx.x*256 + threadIdx.x;   // 512*1280
  int o = i / 1280;
  int kk = i - o*1280;
  int tap = kk >> 8, ic = kk & 255;
  Wf[i] = (_Float16)w[(size_t)o*1280 + ic*5 + tap];
}

// ------- Wq 2-term fp16 split (row-major 256x256) -------
__global__ __launch_bounds__(256) void k_qwprep(const float* __restrict__ W,
    _Float16* __restrict__ Wh, _Float16* __restrict__ Wl)
{
  int i = blockIdx.x*256 + threadIdx.x;   // 65536
  float f = W[i];
  _Float16 h = (_Float16)f;
  Wh[i] = h;
  Wl[i] = (_Float16)(f - (float)h);
}

// ------- W_lin 2-term fp16 split, padded: (256,80) -> [256][96] -------
__global__ __launch_bounds__(256) void k_lwprep(const float* __restrict__ W,
    _Float16* __restrict__ Wh, _Float16* __restrict__ Wl)
{
  int i = blockIdx.x*256 + threadIdx.x;   // 256*96
  int d = i / 96, k = i - d*96;
  float f = (k < INDIM) ? W[d*INDIM + k] : 0.f;
  _Float16 h = (_Float16)f;
  Wh[i] = h;
  Wl[i] = (_Float16)(f - (float)h);
}

// ------- W_proj 2-term fp16 split (row-major 80x256) -------
__global__ __launch_bounds__(256) void k_pwprep(const float* __restrict__ W,
    _Float16* __restrict__ Wh, _Float16* __restrict__ Wl)
{
  int i = blockIdx.x*256 + threadIdx.x;   // 80*256
  float f = W[i];
  _Float16 h = (_Float16)f;
  Wh[i] = h;
  Wl[i] = (_Float16)(f - (float)h);
}

// ------- enc prep: Eh = fp16(enc) [b][s][d];  EVt = fp16(enc+emb) transposed [b][d][s] ---
__global__ __launch_bounds__(256) void k_eprep(const float* __restrict__ enc,
    const float* __restrict__ emb, _Float16* __restrict__ Eh,
    _Float16* __restrict__ EVt)
{
  __shared__ float ls[64][65];
  int blk = blockIdx.x;                  // 32 b * 16 st * 4 dt = 2048
  int dt = blk & 3, st = (blk>>2) & 15, b = blk >> 6;
  int s0 = st*64, d0 = dt*64;
  int tid = threadIdx.x;
  for (int k=0;k<16;k++){
    int idx = k*256 + tid;
    int r = idx >> 6, c = idx & 63;
    size_t gi = ((size_t)b*TE + s0 + r)*DIM + d0 + c;
    float e = enc[gi];
    ls[r][c] = e + emb[gi];
    Eh[gi] = (_Float16)e;
  }
  __syncthreads();
  for (int k=0;k<16;k++){
    int idx = k*256 + tid;
    int r = idx >> 6, c = idx & 63;
    EVt[((size_t)b*DIM + d0 + r)*TE + s0 + c] = (_Float16)ls[c][r];
  }
}

// ---------- input linear + shift-right as fp16 MFMA: X = shift(mel) @ W_lin^T ----------
__global__ __launch_bounds__(256) void k_lin_mfma(const float* __restrict__ mel,
    const _Float16* __restrict__ Wh, const _Float16* __restrict__ Wl,
    const float* __restrict__ bias, _Float16* __restrict__ X)
{
  __shared__ __align__(16) _Float16 ms[64*104];   // 64 rows x 96 cols (pad 104)
  int blk = blockIdx.x;                 // 1024: 32 b x 32 t-tiles
  int b = blk >> 5;
  int t0 = (blk & 31) << 6;
  int tid = threadIdx.x;

  for (int i = tid; i < 64*12; i += 256){
    int row = i / 12, cg = (i - row*12) * 8;
    int t = t0 + row - 1;               // shifted: X[t] = lin(mel[t-1])
    f16x8 v = {};
    if (t >= 0 && cg < INDIM){
      const float4* p = (const float4*)(mel + ((size_t)b*TD + t)*INDIM + cg);
      float4 f0 = p[0], f1 = p[1];
      v[0]=(_Float16)f0.x; v[1]=(_Float16)f0.y; v[2]=(_Float16)f0.z; v[3]=(_Float16)f0.w;
      v[4]=(_Float16)f1.x; v[5]=(_Float16)f1.y; v[6]=(_Float16)f1.z; v[7]=(_Float16)f1.w;
    }
    *(f16x8*)&ms[row*104 + cg] = v;
  }
  __syncthreads();

  int wave = tid >> 6, lane = tid & 63;
  int l15 = lane & 15, l4 = lane >> 4;
  int mb = wave << 4;

  f16x8 am[3];
  #pragma unroll
  for (int kc=0;kc<3;kc++) am[kc] = *(f16x8*)&ms[(mb + l15)*104 + kc*32 + l4*8];

  for (int dt=0; dt<16; dt++){
    size_t wrow = (size_t)(dt*16 + l15)*96 + l4*8;
    f32x4 a = (f32x4){0.f,0.f,0.f,0.f};
    #pragma unroll
    for (int kc=0;kc<3;kc++){
      f16x8 bh = *(const f16x8*)(Wh + wrow + kc*32);
      f16x8 bl = *(const f16x8*)(Wl + wrow + kc*32);
      a = __builtin_amdgcn_mfma_f32_16x16x32_f16(am[kc], bh, a, 0,0,0);
      a = __builtin_amdgcn_mfma_f32_16x16x32_f16(am[kc], bl, a, 0,0,0);
    }
    int d = dt*16 + l15;
    float bv = bias[d];
    #pragma unroll
    for (int r=0;r<4;r++){
      int m = mb + l4*4 + r;
      int t = t0 + m;
      X[((size_t)b*TD + t)*DIM + d] = (t==0) ? (_Float16)0.f : (_Float16)(a[r] + bv);
    }
  }
}

// ---------------- conv-GLU as fp16 MFMA GEMM ----------------
template<int TIN_F32, int TOUT_F32>
__global__ __launch_bounds__(256) void k_conv_mfma(const void* __restrict__ Xin_,
    const _Float16* __restrict__ Wf, const float* __restrict__ bias,
    void* __restrict__ Hout_)
{
  __shared__ __align__(16) _Float16 as[68*264];   // 35.9 KB
  int id = blockIdx.x;
  int dtile = id & 3, mtile = id >> 2;
  int b = mtile >> 5;
  int t0 = (mtile & 31) << 6;
  int d0 = dtile << 6;
  int tid = threadIdx.x;

  for (int i = tid; i < 68*32; i += 256){
    int row = i >> 5, cg = (i & 31) << 3;
    int t = t0 - 4 + row;
    f16x8 v = {};
    if (t >= 0){
      if (TIN_F32){
        const float4* p = (const float4*)((const float*)Xin_ + ((size_t)b*TD + t)*DIM + cg);
        float4 f0 = p[0], f1 = p[1];
        v[0]=(_Float16)f0.x; v[1]=(_Float16)f0.y; v[2]=(_Float16)f0.z; v[3]=(_Float16)f0.w;
        v[4]=(_Float16)f1.x; v[5]=(_Float16)f1.y; v[6]=(_Float16)f1.z; v[7]=(_Float16)f1.w;
      } else {
        v = *(const f16x8*)((const _Float16*)Xin_ + ((size_t)b*TD + t)*DIM + cg);
      }
    }
    *(f16x8*)&as[row*264 + cg] = v;
  }
  __syncthreads();

  int lane = tid & 63, wave = tid >> 6;
  int l15 = lane & 15, l4 = lane >> 4;
  int dA = d0 + (wave << 4) + l15;

  const _Float16* pA = Wf + (size_t)dA*1280 + l4*8;
  const _Float16* pG = Wf + (size_t)(256 + dA)*1280 + l4*8;

  f32x4 aca[4], acg[4];
  #pragma unroll
  for (int mt=0;mt<4;mt++){ aca[mt]=(f32x4){0.f,0.f,0.f,0.f}; acg[mt]=(f32x4){0.f,0.f,0.f,0.f}; }

  f16x8 bA = *(const f16x8*)pA;
  f16x8 bG = *(const f16x8*)pG;
  #pragma unroll
  for (int kc = 0; kc < 40; ++kc){
    f16x8 nA = bA, nG = bG;
    if (kc < 39){
      nA = *(const f16x8*)(pA + (kc+1)*32);
      nG = *(const f16x8*)(pG + (kc+1)*32);
    }
    int tap = kc >> 3;
    int ic0 = (kc & 7) << 5;
    int abase = (l15 + tap)*264 + ic0 + l4*8;
    #pragma unroll
    for (int mt=0;mt<4;mt++){
      f16x8 av = *(f16x8*)&as[abase + mt*16*264];
      aca[mt] = __builtin_amdgcn_mfma_f32_16x16x32_f16(av, bA, aca[mt], 0,0,0);
      acg[mt] = __builtin_amdgcn_mfma_f32_16x16x32_f16(av, bG, acg[mt], 0,0,0);
    }
    bA = nA; bG = nG;
  }

  const float is2 = 0.7071067811865476f;
  float ba = bias[dA], bg = bias[256 + dA];
  #pragma unroll
  for (int mt=0; mt<4; mt++){
    #pragma unroll
    for (int r=0;r<4;r++){
      int m = mt*16 + l4*4 + r;
      size_t orow = ((size_t)b*TD + t0 + m)*DIM;
      float xr = TIN_F32 ? ((const float*)Xin_)[orow + dA]
                         : (float)as[(m+4)*264 + dA];
      float a = aca[mt][r] + ba;
      float g = acg[mt][r] + bg;
      float o = (a*sigmoidf_(g) + xr)*is2;
      if (TOUT_F32) ((float*)Hout_)[orow + dA] = o;
      else          ((_Float16*)Hout_)[orow + dA] = (_Float16)o;
    }
  }
}

// ---------- fused q-linear + flash attention + residual ----------
// Measured-best (348us) structure restored verbatim, with exactly two edits:
//  (1) P exchange pb -> flat [64][64] with Kb-style XOR-granule swizzle on both
//      sides: kills the 8-way bank conflict on the PV ds_read_b128 of P.
//  (2) V fragment loads hoisted ABOVE the stage DMAs: vmcnt is FIFO, so PV's
//      wait on vv no longer drains the next-chunk K prefetch (it stays in
//      flight until the loop-end __syncthreads).
__device__ __forceinline__ void stage_k(const _Float16* __restrict__ Ehb,
    _Float16* __restrict__ dst, int srow0, int wave, int lane)
{
  int r2 = lane >> 5, cu = lane & 31;
  #pragma unroll
  for (int ii=0; ii<8; ii++){
    int row = (ii*4 + wave)*2 + r2;                       // 0..63
    cp16(Ehb + (size_t)(srow0 + row)*DIM + ((cu ^ (row & 7)) << 3),
         dst + (ii*4 + wave)*512);                        // wave-uniform LDS base
  }
}

__global__ __launch_bounds__(256) void k_attn(float* __restrict__ H,
    const _Float16* __restrict__ Wqh, const _Float16* __restrict__ Wql,
    const float* __restrict__ bq,
    const _Float16* __restrict__ Eh, const _Float16* __restrict__ EVt)
{
  __shared__ __align__(16) _Float16 Kb[2][64*256];   // 64 KB K double-buffer (swizzled)
  __shared__ __align__(16) _Float16 pbf[64*64];      // 8 KB P chunk (XOR-granule swizzled)
  __shared__ float alphas[64];
  __shared__ float linvs[64];

  int i = blockIdx.x;                   // XCD swizzle: same-batch blocks share an XCD
  int b = (i & 7) | ((i >> 8) << 3);
  int t0 = ((i >> 3) & 31) << 6;
  int tid = threadIdx.x;
  int wave = tid >> 6, lane = tid & 63;
  int l15 = lane & 15, l4 = lane >> 4;
  int mb = wave << 4;

  const _Float16* Ehb = Eh + (size_t)b*TE*DIM;
  const _Float16* EVb = EVt + (size_t)b*DIM*TE;

  // prefetch K chunk 0 into Kb[0] (latency hidden under the whole q-linear)
  stage_k(Ehb, &Kb[0][0], 0, wave, lane);

  // ---- q-linear (2-term fp16) ----
  f16x8 ah[8];
  {
    const float* hrow = H + ((size_t)b*TD + t0 + mb + l15)*DIM;
    #pragma unroll
    for (int kc=0;kc<8;kc++){
      const float4* p = (const float4*)(hrow + kc*32 + l4*8);
      float4 f0 = p[0], f1 = p[1];
      f16x8 v;
      v[0]=(_Float16)f0.x; v[1]=(_Float16)f0.y; v[2]=(_Float16)f0.z; v[3]=(_Float16)f0.w;
      v[4]=(_Float16)f1.x; v[5]=(_Float16)f1.y; v[6]=(_Float16)f1.z; v[7]=(_Float16)f1.w;
      ah[kc] = v;
    }
  }

  f32x4 qacc[16];
  for (int ot=0;ot<16;ot++){
    size_t wrow = (size_t)(ot*16 + l15)*256 + l4*8;
    f32x4 a = (f32x4){0.f,0.f,0.f,0.f};
    #pragma unroll
    for (int kc=0;kc<8;kc++){
      f16x8 bh = *(const f16x8*)(Wqh + wrow + kc*32);
      f16x8 bl = *(const f16x8*)(Wql + wrow + kc*32);
      a = __builtin_amdgcn_mfma_f32_16x16x32_f16(ah[kc], bh, a, 0,0,0);
      a = __builtin_amdgcn_mfma_f32_16x16x32_f16(ah[kc], bl, a, 0,0,0);
    }
    qacc[ot] = a;
  }
  #pragma unroll
  for (int ot=0;ot<16;ot++){
    float bqv = bq[ot*16 + l15];
    #pragma unroll
    for (int r=0;r<4;r++) qacc[ot][r] += bqv;
  }

  // ---- transit Q hi/lo through Kb[1] (one-time; done before Kb[1] is prefetched) ----
  #pragma unroll
  for (int ot=0;ot<16;ot++){
    int o = ot*16 + l15;
    #pragma unroll
    for (int r=0;r<4;r++)
      Kb[1][(mb + l4*4 + r)*256 + o] = (_Float16)qacc[ot][r];
  }
  __syncthreads();
  f16x8 aqh[8];
  #pragma unroll
  for (int kc=0;kc<8;kc++) aqh[kc] = *(f16x8*)&Kb[1][(mb + l15)*256 + kc*32 + l4*8];
  __syncthreads();
  #pragma unroll
  for (int ot=0;ot<16;ot++){
    int o = ot*16 + l15;
    #pragma unroll
    for (int r=0;r<4;r++){
      float v = qacc[ot][r];
      _Float16 h = (_Float16)v;
      Kb[1][(mb + l4*4 + r)*256 + o] = (_Float16)(v - (float)h);
    }
  }
  __syncthreads();
  f16x8 aql[8];
  #pragma unroll
  for (int kc=0;kc<8;kc++) aql[kc] = *(f16x8*)&Kb[1][(mb + l15)*256 + kc*32 + l4*8];
  __syncthreads();                       // Kb[1] free for prefetch from here on

  f32x4 oacc[4][4];                      // [m-tile][d-tile], d-split: this wave owns dq..dq+63
  #pragma unroll
  for (int mt=0;mt<4;mt++)
    #pragma unroll
    for (int dt=0;dt<4;dt++) oacc[mt][dt] = (f32x4){0.f,0.f,0.f,0.f};
  float mrun[4], lrun[4];
  #pragma unroll
  for (int r=0;r<4;r++){ mrun[r] = -3.0e38f; lrun[r] = 0.f; }
  int dq = wave << 6;
  int sw = l15 & 7;

  #pragma unroll 2
  for (int c = 0; c < 16; ++c){
    int cur = c & 1;
    int s0 = c << 6;

    // ---- V fragments FIRST (edit 2): issued before the stage DMAs so PV's
    //      counted vmcnt wait on vv leaves the K prefetch in flight ----
    f16x8 vv[2][4];
    #pragma unroll
    for (int kp=0;kp<2;kp++)
      #pragma unroll
      for (int dt=0;dt<4;dt++)
        vv[kp][dt] = *(const f16x8*)(EVb + (size_t)(dq + dt*16 + l15)*TE + s0 + kp*32 + l4*8);

    // prefetch next K chunk into the other buffer; drains at loop-end barrier
    if (c < 15) stage_k(Ehb, &Kb[cur^1][0], s0 + 64, wave, lane);

    // ---- QK^T (reads swizzled Kb[cur]) ----
    f32x4 sacc[4];
    #pragma unroll
    for (int st=0;st<4;st++){
      const _Float16* kb = &Kb[cur][(st*16 + l15)*256];
      f32x4 a = (f32x4){0.f,0.f,0.f,0.f};
      #pragma unroll
      for (int kc=0;kc<8;kc++){
        f16x8 bh = *(const f16x8*)(kb + (((kc*4 + l4) ^ sw) << 3));
        a = __builtin_amdgcn_mfma_f32_16x16x32_f16(aqh[kc], bh, a, 0,0,0);
        a = __builtin_amdgcn_mfma_f32_16x16x32_f16(aql[kc], bh, a, 0,0,0);
      }
      sacc[st] = a;
    }

    // ---- online softmax (owner wave: rows mb..mb+15) ----
    float alpha[4];
    #pragma unroll
    for (int r=0;r<4;r++){
      float cm = fmaxf(fmaxf(sacc[0][r], sacc[1][r]), fmaxf(sacc[2][r], sacc[3][r]));
      cm = fmaxf(cm, __shfl_xor(cm, 1));
      cm = fmaxf(cm, __shfl_xor(cm, 2));
      cm = fmaxf(cm, __shfl_xor(cm, 4));
      cm = fmaxf(cm, __shfl_xor(cm, 8));
      float mnew = fmaxf(mrun[r], cm);
      alpha[r] = __expf(mrun[r] - mnew);
      mrun[r] = mnew;
      float ps = 0.f;
      #pragma unroll
      for (int st=0;st<4;st++){
        float p = __expf(sacc[st][r] - mnew);
        sacc[st][r] = p;
        ps += p;
      }
      ps += __shfl_xor(ps, 1);
      ps += __shfl_xor(ps, 2);
      ps += __shfl_xor(ps, 4);
      ps += __shfl_xor(ps, 8);
      lrun[r] = lrun[r]*alpha[r] + ps;
    }

    // ---- publish P (edit 1: XOR-granule swizzled flat [64][64]) and alpha ----
    #pragma unroll
    for (int st=0;st<4;st++)
      #pragma unroll
      for (int r=0;r<4;r++){
        int row = mb + l4*4 + r;
        pbf[row*64 + ((st*16 + l15) ^ ((row & 7) << 3))] = (_Float16)sacc[st][r];
      }
    if (l15 == 0){
      #pragma unroll
      for (int r=0;r<4;r++) alphas[mb + l4*4 + r] = alpha[r];
    }
    // raw barrier: wait LDS writes only — K prefetch stays in flight (no vmcnt drain)
    asm volatile("s_waitcnt lgkmcnt(0)" ::: "memory");
    __builtin_amdgcn_s_barrier();

    // ---- rescale (skipped when no row saw a new max) + PV (d-split) ----
    float avs[4][4];
    bool need = false;
    #pragma unroll
    for (int mt=0;mt<4;mt++)
      #pragma unroll
      for (int r=0;r<4;r++){
        float av = alphas[mt*16 + l4*4 + r];
        avs[mt][r] = av;
        need |= (av != 1.0f);
      }
    if (need){
      #pragma unroll
      for (int mt=0;mt<4;mt++)
        #pragma unroll
        for (int r=0;r<4;r++){
          float av = avs[mt][r];
          #pragma unroll
          for (int dt=0;dt<4;dt++) oacc[mt][dt][r] *= av;
        }
    }
    #pragma unroll
    for (int kp=0;kp<2;kp++){
      f16x8 pa[4];
      #pragma unroll
      for (int mt=0;mt<4;mt++)
        pa[mt] = *(f16x8*)&pbf[(mt*16 + l15)*64 + ((kp*32 + l4*8) ^ (sw << 3))];
      #pragma unroll
      for (int dt=0;dt<4;dt++){
        #pragma unroll
        for (int mt=0;mt<4;mt++)
          oacc[mt][dt] = __builtin_amdgcn_mfma_f32_16x16x32_f16(pa[mt], vv[kp][dt], oacc[mt][dt], 0,0,0);
      }
    }
    __syncthreads();   // pbf reads done + K prefetch drained (vmcnt 0) before next chunk
  }

  // ---- epilogue: publish 1/l, then H += O/l (each wave writes its d-quarter) ----
  if (l15 == 0){
    #pragma unroll
    for (int r=0;r<4;r++) linvs[mb + l4*4 + r] = 1.f / lrun[r];
  }
  __syncthreads();
  #pragma unroll
  for (int mt=0;mt<4;mt++){
    #pragma unroll
    for (int r=0;r<4;r++){
      float li = linvs[mt*16 + l4*4 + r];
      int t = t0 + mt*16 + l4*4 + r;
      float* hp = &H[((size_t)b*TD + t)*DIM + dq];
      #pragma unroll
      for (int dt=0;dt<4;dt++)
        hp[dt*16 + l15] += oacc[mt][dt][r] * li;
    }
  }
}

// ---------- output projection as fp16 MFMA: out = Pb @ (Wph+Wpl)^T + bias ----------
__global__ __launch_bounds__(256) void k_proj_mfma(const _Float16* __restrict__ Hin,
    const _Float16* __restrict__ Wh, const _Float16* __restrict__ Wl,
    const float* __restrict__ bias, float* __restrict__ out)
{
  int blk = blockIdx.x;                 // 1024: 32 b x 32 t-tiles
  int b = blk >> 5;
  int t0 = (blk & 31) << 6;
  int tid = threadIdx.x;
  int wave = tid >> 6, lane = tid & 63;
  int l15 = lane & 15, l4 = lane >> 4;
  int mb = wave << 4;

  f16x8 ah[8];
  const _Float16* hrow = Hin + ((size_t)b*TD + t0 + mb + l15)*DIM;
  #pragma unroll
  for (int kc=0;kc<8;kc++) ah[kc] = *(const f16x8*)(hrow + kc*32 + l4*8);

  #pragma unroll
  for (int nt=0; nt<5; nt++){
    size_t wrow = (size_t)(nt*16 + l15)*256 + l4*8;
    f32x4 a = (f32x4){0.f,0.f,0.f,0.f};
    #pragma unroll
    for (int kc=0;kc<8;kc++){
      f16x8 bh = *(const f16x8*)(Wh + wrow + kc*32);
      f16x8 bl = *(const f16x8*)(Wl + wrow + kc*32);
      a = __builtin_amdgcn_mfma_f32_16x16x32_f16(ah[kc], bh, a, 0,0,0);
      a = __builtin_amdgcn_mfma_f32_16x16x32_f16(ah[kc], bl, a, 0,0,0);
    }
    int n = nt*16 + l15;
    float bv = bias[n];
    #pragma unroll
    for (int r=0;r<4;r++){
      int t = t0 + mb + l4*4 + r;
      out[((size_t)b*TD + t)*INDIM + n] = a[r] + bv;
    }
  }
}

extern "C" void kernel_launch(void* const* d_in, const int* in_sizes, int n_in,
                              void* d_out, int out_size, void* d_ws, size_t ws_size,
                              hipStream_t stream) {
  const float* enc   = (const float*)d_in[0];
  const float* emb   = (const float*)d_in[1];
  const float* mel   = (const float*)d_in[2];
  const float* W_lin = (const float*)d_in[3];
  const float* b_lin = (const float*)d_in[4];
  const float* w0    = (const float*)d_in[5];
  const float* b0    = (const float*)d_in[6];
  const float* w1    = (const float*)d_in[7];
  const float* b1    = (const float*)d_in[8];
  const float* Wq    = (const float*)d_in[9];
  const float* bq    = (const float*)d_in[10];
  const float* Wp    = (const float*)d_in[11];
  const float* bp    = (const float*)d_in[12];
  float* out = (float*)d_out;

  const size_t NTOK = (size_t)BB*TD*DIM;           // 16.78M
  const size_t NE   = (size_t)BB*TE*DIM;           // 8.39M
  _Float16* Xb  = (_Float16*)d_ws;
  float*    H   = (float*)(Xb + NTOK);
  _Float16* Wf0 = (_Float16*)(H + NTOK);
  _Float16* Wf1 = Wf0 + (size_t)512*1280;
  _Float16* Wqh = Wf1 + (size_t)512*1280;
  _Float16* Wql = Wqh + 65536;
  _Float16* Wlh = Wql + 65536;                     // 256*96
  _Float16* Wll = Wlh + 24576;
  _Float16* Wph = Wll + 24576;                     // 80*256
  _Float16* Wpl = Wph + 20480;
  _Float16* Eh  = Xb;                              // after conv0 consumes Xb
  _Float16* EVt = Xb + NE;
  _Float16* Pb  = Xb;                              // after attn consumes Eh/EVt

  k_wprep    <<<2560, 256, 0, stream>>>(w0, Wf0);
  k_wprep    <<<2560, 256, 0, stream>>>(w1, Wf1);
  k_qwprep   <<<256,  256, 0, stream>>>(Wq, Wqh, Wql);
  k_lwprep   <<<96,   256, 0, stream>>>(W_lin, Wlh, Wll);
  k_pwprep   <<<80,   256, 0, stream>>>(Wp, Wph, Wpl);
  k_lin_mfma <<<1024, 256, 0, stream>>>(mel, Wlh, Wll, b_lin, Xb);
  k_conv_mfma<0,1><<<4096, 256, 0, stream>>>(Xb, Wf0, b0, H);
  k_eprep    <<<2048, 256, 0, stream>>>(enc, emb, Eh, EVt);
  k_attn     <<<1024, 256, 0, stream>>>(H, Wqh, Wql, bq, Eh, EVt);
  k_conv_mfma<1,0><<<4096, 256, 0, stream>>>(H, Wf1, b1, Pb);
  k_proj_mfma<<<1024, 256, 0, stream>>>(Pb, Wph, Wpl, bp, out);
}

// Round 8
// 845.353 us; speedup vs baseline: 1.0661x; 1.0661x over previous
//
#include <hip/hip_runtime.h>
#include <math.h>

#define BB 32
#define TD 2048
#define TE 1024
#define DIM 256
#define INDIM 80

typedef __attribute__((ext_vector_type(8))) _Float16 f16x8;
typedef __attribute__((ext_vector_type(4))) float f32x4;

__device__ __forceinline__ float sigmoidf_(float x){ return 1.f/(1.f+__expf(-x)); }

// async 16B global->LDS copy (direct DMA, no VGPR round-trip)
__device__ __forceinline__ void cp16(const _Float16* g, _Float16* l){
  __builtin_amdgcn_global_load_lds(
      (const __attribute__((address_space(1))) unsigned int*)g,
      (__attribute__((address_space(3))) unsigned int*)l, 16, 0, 0);
}

// ------- conv weight reorder: w(512,256,5) f32 -> Wf[o][tap*256+ic] fp16 -------
__global__ __launch_bounds__(256) void k_wprep(const float* __restrict__ w,
    _Float16* __restrict__ Wf)
{
  int i = blockIdx.x*256 + threadIdx.x;   // 512*1280
  int o = i / 1280;
  int kk = i - o*1280;
  int tap = kk >> 8, ic = kk & 255;
  Wf[i] = (_Float16)w[(size_t)o*1280 + ic*5 + tap];
}

// ------- Wq 2-term fp16 split (row-major 256x256) -------
__global__ __launch_bounds__(256) void k_qwprep(const float* __restrict__ W,
    _Float16* __restrict__ Wh, _Float16* __restrict__ Wl)
{
  int i = blockIdx.x*256 + threadIdx.x;   // 65536
  float f = W[i];
  _Float16 h = (_Float16)f;
  Wh[i] = h;
  Wl[i] = (_Float16)(f - (float)h);
}

// ------- W_lin 2-term fp16 split, padded: (256,80) -> [256][96] -------
__global__ __launch_bounds__(256) void k_lwprep(const float* __restrict__ W,
    _Float16* __restrict__ Wh, _Float16* __restrict__ Wl)
{
  int i = blockIdx.x*256 + threadIdx.x;   // 256*96
  int d = i / 96, k = i - d*96;
  float f = (k < INDIM) ? W[d*INDIM + k] : 0.f;
  _Float16 h = (_Float16)f;
  Wh[i] = h;
  Wl[i] = (_Float16)(f - (float)h);
}

// ------- W_proj 2-term fp16 split (row-major 80x256) -------
__global__ __launch_bounds__(256) void k_pwprep(const float* __restrict__ W,
    _Float16* __restrict__ Wh, _Float16* __restrict__ Wl)
{
  int i = blockIdx.x*256 + threadIdx.x;   // 80*256
  float f = W[i];
  _Float16 h = (_Float16)f;
  Wh[i] = h;
  Wl[i] = (_Float16)(f - (float)h);
}

// ------- enc prep: Eh = fp16(enc) [b][s][d];  EVt = fp16(enc+emb) transposed [b][d][s] ---
__global__ __launch_bounds__(256) void k_eprep(const float* __restrict__ enc,
    const float* __restrict__ emb, _Float16* __restrict__ Eh,
    _Float16* __restrict__ EVt)
{
  __shared__ float ls[64][65];
  int blk = blockIdx.x;                  // 32 b * 16 st * 4 dt = 2048
  int dt = blk & 3, st = (blk>>2) & 15, b = blk >> 6;
  int s0 = st*64, d0 = dt*64;
  int tid = threadIdx.x;
  for (int k=0;k<16;k++){
    int idx = k*256 + tid;
    int r = idx >> 6, c = idx & 63;
    size_t gi = ((size_t)b*TE + s0 + r)*DIM + d0 + c;
    float e = enc[gi];
    ls[r][c] = e + emb[gi];
    Eh[gi] = (_Float16)e;
  }
  __syncthreads();
  for (int k=0;k<16;k++){
    int idx = k*256 + tid;
    int r = idx >> 6, c = idx & 63;
    EVt[((size_t)b*DIM + d0 + r)*TE + s0 + c] = (_Float16)ls[c][r];
  }
}

// ---------- input linear + shift-right as fp16 MFMA: X = shift(mel) @ W_lin^T ----------
__global__ __launch_bounds__(256) void k_lin_mfma(const float* __restrict__ mel,
    const _Float16* __restrict__ Wh, const _Float16* __restrict__ Wl,
    const float* __restrict__ bias, _Float16* __restrict__ X)
{
  __shared__ __align__(16) _Float16 ms[64*104];   // 64 rows x 96 cols (pad 104)
  int blk = blockIdx.x;                 // 1024: 32 b x 32 t-tiles
  int b = blk >> 5;
  int t0 = (blk & 31) << 6;
  int tid = threadIdx.x;

  for (int i = tid; i < 64*12; i += 256){
    int row = i / 12, cg = (i - row*12) * 8;
    int t = t0 + row - 1;               // shifted: X[t] = lin(mel[t-1])
    f16x8 v = {};
    if (t >= 0 && cg < INDIM){
      const float4* p = (const float4*)(mel + ((size_t)b*TD + t)*INDIM + cg);
      float4 f0 = p[0], f1 = p[1];
      v[0]=(_Float16)f0.x; v[1]=(_Float16)f0.y; v[2]=(_Float16)f0.z; v[3]=(_Float16)f0.w;
      v[4]=(_Float16)f1.x; v[5]=(_Float16)f1.y; v[6]=(_Float16)f1.z; v[7]=(_Float16)f1.w;
    }
    *(f16x8*)&ms[row*104 + cg] = v;
  }
  __syncthreads();

  int wave = tid >> 6, lane = tid & 63;
  int l15 = lane & 15, l4 = lane >> 4;
  int mb = wave << 4;

  f16x8 am[3];
  #pragma unroll
  for (int kc=0;kc<3;kc++) am[kc] = *(f16x8*)&ms[(mb + l15)*104 + kc*32 + l4*8];

  for (int dt=0; dt<16; dt++){
    size_t wrow = (size_t)(dt*16 + l15)*96 + l4*8;
    f32x4 a = (f32x4){0.f,0.f,0.f,0.f};
    #pragma unroll
    for (int kc=0;kc<3;kc++){
      f16x8 bh = *(const f16x8*)(Wh + wrow + kc*32);
      f16x8 bl = *(const f16x8*)(Wl + wrow + kc*32);
      a = __builtin_amdgcn_mfma_f32_16x16x32_f16(am[kc], bh, a, 0,0,0);
      a = __builtin_amdgcn_mfma_f32_16x16x32_f16(am[kc], bl, a, 0,0,0);
    }
    int d = dt*16 + l15;
    float bv = bias[d];
    #pragma unroll
    for (int r=0;r<4;r++){
      int m = mb + l4*4 + r;
      int t = t0 + m;
      X[((size_t)b*TD + t)*DIM + d] = (t==0) ? (_Float16)0.f : (_Float16)(a[r] + bv);
    }
  }
}

// ---------------- conv-GLU as fp16 MFMA GEMM ----------------
template<int TIN_F32, int TOUT_F32>
__global__ __launch_bounds__(256) void k_conv_mfma(const void* __restrict__ Xin_,
    const _Float16* __restrict__ Wf, const float* __restrict__ bias,
    void* __restrict__ Hout_)
{
  __shared__ __align__(16) _Float16 as[68*264];   // 35.9 KB
  int id = blockIdx.x;
  int dtile = id & 3, mtile = id >> 2;
  int b = mtile >> 5;
  int t0 = (mtile & 31) << 6;
  int d0 = dtile << 6;
  int tid = threadIdx.x;

  for (int i = tid; i < 68*32; i += 256){
    int row = i >> 5, cg = (i & 31) << 3;
    int t = t0 - 4 + row;
    f16x8 v = {};
    if (t >= 0){
      if (TIN_F32){
        const float4* p = (const float4*)((const float*)Xin_ + ((size_t)b*TD + t)*DIM + cg);
        float4 f0 = p[0], f1 = p[1];
        v[0]=(_Float16)f0.x; v[1]=(_Float16)f0.y; v[2]=(_Float16)f0.z; v[3]=(_Float16)f0.w;
        v[4]=(_Float16)f1.x; v[5]=(_Float16)f1.y; v[6]=(_Float16)f1.z; v[7]=(_Float16)f1.w;
      } else {
        v = *(const f16x8*)((const _Float16*)Xin_ + ((size_t)b*TD + t)*DIM + cg);
      }
    }
    *(f16x8*)&as[row*264 + cg] = v;
  }
  __syncthreads();

  int lane = tid & 63, wave = tid >> 6;
  int l15 = lane & 15, l4 = lane >> 4;
  int dA = d0 + (wave << 4) + l15;

  const _Float16* pA = Wf + (size_t)dA*1280 + l4*8;
  const _Float16* pG = Wf + (size_t)(256 + dA)*1280 + l4*8;

  f32x4 aca[4], acg[4];
  #pragma unroll
  for (int mt=0;mt<4;mt++){ aca[mt]=(f32x4){0.f,0.f,0.f,0.f}; acg[mt]=(f32x4){0.f,0.f,0.f,0.f}; }

  f16x8 bA = *(const f16x8*)pA;
  f16x8 bG = *(const f16x8*)pG;
  #pragma unroll
  for (int kc = 0; kc < 40; ++kc){
    f16x8 nA = bA, nG = bG;
    if (kc < 39){
      nA = *(const f16x8*)(pA + (kc+1)*32);
      nG = *(const f16x8*)(pG + (kc+1)*32);
    }
    int tap = kc >> 3;
    int ic0 = (kc & 7) << 5;
    int abase = (l15 + tap)*264 + ic0 + l4*8;
    #pragma unroll
    for (int mt=0;mt<4;mt++){
      f16x8 av = *(f16x8*)&as[abase + mt*16*264];
      aca[mt] = __builtin_amdgcn_mfma_f32_16x16x32_f16(av, bA, aca[mt], 0,0,0);
      acg[mt] = __builtin_amdgcn_mfma_f32_16x16x32_f16(av, bG, acg[mt], 0,0,0);
    }
    bA = nA; bG = nG;
  }

  const float is2 = 0.7071067811865476f;
  float ba = bias[dA], bg = bias[256 + dA];
  #pragma unroll
  for (int mt=0; mt<4; mt++){
    #pragma unroll
    for (int r=0;r<4;r++){
      int m = mt*16 + l4*4 + r;
      size_t orow = ((size_t)b*TD + t0 + m)*DIM;
      float xr = TIN_F32 ? ((const float*)Xin_)[orow + dA]
                         : (float)as[(m+4)*264 + dA];
      float a = aca[mt][r] + ba;
      float g = acg[mt][r] + bg;
      float o = (a*sigmoidf_(g) + xr)*is2;
      if (TOUT_F32) ((float*)Hout_)[orow + dA] = o;
      else          ((_Float16*)Hout_)[orow + dA] = (_Float16)o;
    }
  }
}

// ---------- fused q-linear + flash attention + residual ----------
// The measured-best 348us structure, byte-for-byte, with ONE global change:
// H is fp16 end-to-end (conv0 out -> q-linear in -> residual RMW -> conv1 in).
// Prologue becomes direct f16x8 loads (no f32->f16 cvts); epilogue RMWs fp16.
__device__ __forceinline__ void stage_k(const _Float16* __restrict__ Ehb,
    _Float16* __restrict__ dst, int srow0, int wave, int lane)
{
  int r2 = lane >> 5, cu = lane & 31;
  #pragma unroll
  for (int ii=0; ii<8; ii++){
    int row = (ii*4 + wave)*2 + r2;                       // 0..63
    cp16(Ehb + (size_t)(srow0 + row)*DIM + ((cu ^ (row & 7)) << 3),
         dst + (ii*4 + wave)*512);                        // wave-uniform LDS base
  }
}

__global__ __launch_bounds__(256) void k_attn(_Float16* __restrict__ H,
    const _Float16* __restrict__ Wqh, const _Float16* __restrict__ Wql,
    const float* __restrict__ bq,
    const _Float16* __restrict__ Eh, const _Float16* __restrict__ EVt)
{
  __shared__ __align__(16) _Float16 Kb[2][64*256];   // 64 KB K double-buffer (swizzled)
  __shared__ __align__(16) _Float16 pb[64][72];      // 9.2 KB P chunk (cross-wave)
  __shared__ float alphas[64];
  __shared__ float linvs[64];

  int i = blockIdx.x;                   // XCD swizzle: same-batch blocks share an XCD
  int b = (i & 7) | ((i >> 8) << 3);
  int t0 = ((i >> 3) & 31) << 6;
  int tid = threadIdx.x;
  int wave = tid >> 6, lane = tid & 63;
  int l15 = lane & 15, l4 = lane >> 4;
  int mb = wave << 4;

  const _Float16* Ehb = Eh + (size_t)b*TE*DIM;
  const _Float16* EVb = EVt + (size_t)b*DIM*TE;

  // prefetch K chunk 0 into Kb[0] (latency hidden under the whole q-linear)
  stage_k(Ehb, &Kb[0][0], 0, wave, lane);

  // ---- q-linear (2-term fp16); H is fp16 -> direct fragment loads ----
  f16x8 ah[8];
  {
    const _Float16* hrow = H + ((size_t)b*TD + t0 + mb + l15)*DIM;
    #pragma unroll
    for (int kc=0;kc<8;kc++) ah[kc] = *(const f16x8*)(hrow + kc*32 + l4*8);
  }

  f32x4 qacc[16];
  for (int ot=0;ot<16;ot++){
    size_t wrow = (size_t)(ot*16 + l15)*256 + l4*8;
    f32x4 a = (f32x4){0.f,0.f,0.f,0.f};
    #pragma unroll
    for (int kc=0;kc<8;kc++){
      f16x8 bh = *(const f16x8*)(Wqh + wrow + kc*32);
      f16x8 bl = *(const f16x8*)(Wql + wrow + kc*32);
      a = __builtin_amdgcn_mfma_f32_16x16x32_f16(ah[kc], bh, a, 0,0,0);
      a = __builtin_amdgcn_mfma_f32_16x16x32_f16(ah[kc], bl, a, 0,0,0);
    }
    qacc[ot] = a;
  }
  #pragma unroll
  for (int ot=0;ot<16;ot++){
    float bqv = bq[ot*16 + l15];
    #pragma unroll
    for (int r=0;r<4;r++) qacc[ot][r] += bqv;
  }

  // ---- transit Q hi/lo through Kb[1] (one-time; done before Kb[1] is prefetched) ----
  #pragma unroll
  for (int ot=0;ot<16;ot++){
    int o = ot*16 + l15;
    #pragma unroll
    for (int r=0;r<4;r++)
      Kb[1][(mb + l4*4 + r)*256 + o] = (_Float16)qacc[ot][r];
  }
  __syncthreads();
  f16x8 aqh[8];
  #pragma unroll
  for (int kc=0;kc<8;kc++) aqh[kc] = *(f16x8*)&Kb[1][(mb + l15)*256 + kc*32 + l4*8];
  __syncthreads();
  #pragma unroll
  for (int ot=0;ot<16;ot++){
    int o = ot*16 + l15;
    #pragma unroll
    for (int r=0;r<4;r++){
      float v = qacc[ot][r];
      _Float16 h = (_Float16)v;
      Kb[1][(mb + l4*4 + r)*256 + o] = (_Float16)(v - (float)h);
    }
  }
  __syncthreads();
  f16x8 aql[8];
  #pragma unroll
  for (int kc=0;kc<8;kc++) aql[kc] = *(f16x8*)&Kb[1][(mb + l15)*256 + kc*32 + l4*8];
  __syncthreads();                       // Kb[1] free for prefetch from here on

  f32x4 oacc[4][4];                      // [m-tile][d-tile], d-split: this wave owns dq..dq+63
  #pragma unroll
  for (int mt=0;mt<4;mt++)
    #pragma unroll
    for (int dt=0;dt<4;dt++) oacc[mt][dt] = (f32x4){0.f,0.f,0.f,0.f};
  float mrun[4], lrun[4];
  #pragma unroll
  for (int r=0;r<4;r++){ mrun[r] = -3.0e38f; lrun[r] = 0.f; }
  int dq = wave << 6;
  int sw = l15 & 7;

  #pragma unroll 2
  for (int c = 0; c < 16; ++c){
    int cur = c & 1;
    int s0 = c << 6;
    // prefetch next K chunk into the other buffer; drains at loop-end barrier
    if (c < 15) stage_k(Ehb, &Kb[cur^1][0], s0 + 64, wave, lane);

    // ---- QK^T (reads swizzled Kb[cur]) ----
    f32x4 sacc[4];
    #pragma unroll
    for (int st=0;st<4;st++){
      const _Float16* kb = &Kb[cur][(st*16 + l15)*256];
      f32x4 a = (f32x4){0.f,0.f,0.f,0.f};
      #pragma unroll
      for (int kc=0;kc<8;kc++){
        f16x8 bh = *(const f16x8*)(kb + (((kc*4 + l4) ^ sw) << 3));
        a = __builtin_amdgcn_mfma_f32_16x16x32_f16(aqh[kc], bh, a, 0,0,0);
        a = __builtin_amdgcn_mfma_f32_16x16x32_f16(aql[kc], bh, a, 0,0,0);
      }
      sacc[st] = a;
    }

    // ---- V fragments for this wave's d-quarter, direct from global (L2) ----
    f16x8 vv[2][4];
    #pragma unroll
    for (int kp=0;kp<2;kp++)
      #pragma unroll
      for (int dt=0;dt<4;dt++)
        vv[kp][dt] = *(const f16x8*)(EVb + (size_t)(dq + dt*16 + l15)*TE + s0 + kp*32 + l4*8);

    // ---- online softmax (owner wave: rows mb..mb+15) ----
    float alpha[4];
    #pragma unroll
    for (int r=0;r<4;r++){
      float cm = fmaxf(fmaxf(sacc[0][r], sacc[1][r]), fmaxf(sacc[2][r], sacc[3][r]));
      cm = fmaxf(cm, __shfl_xor(cm, 1));
      cm = fmaxf(cm, __shfl_xor(cm, 2));
      cm = fmaxf(cm, __shfl_xor(cm, 4));
      cm = fmaxf(cm, __shfl_xor(cm, 8));
      float mnew = fmaxf(mrun[r], cm);
      alpha[r] = __expf(mrun[r] - mnew);
      mrun[r] = mnew;
      float ps = 0.f;
      #pragma unroll
      for (int st=0;st<4;st++){
        float p = __expf(sacc[st][r] - mnew);
        sacc[st][r] = p;
        ps += p;
      }
      ps += __shfl_xor(ps, 1);
      ps += __shfl_xor(ps, 2);
      ps += __shfl_xor(ps, 4);
      ps += __shfl_xor(ps, 8);
      lrun[r] = lrun[r]*alpha[r] + ps;
    }

    // ---- publish P and alpha ----
    #pragma unroll
    for (int st=0;st<4;st++)
      #pragma unroll
      for (int r=0;r<4;r++)
        pb[mb + l4*4 + r][st*16 + l15] = (_Float16)sacc[st][r];
    if (l15 == 0){
      #pragma unroll
      for (int r=0;r<4;r++) alphas[mb + l4*4 + r] = alpha[r];
    }
    // raw barrier: wait LDS writes only — K prefetch stays in flight (no vmcnt drain)
    asm volatile("s_waitcnt lgkmcnt(0)" ::: "memory");
    __builtin_amdgcn_s_barrier();

    // ---- rescale + PV (d-split: all 64 rows, this wave's 64 d-columns) ----
    #pragma unroll
    for (int mt=0;mt<4;mt++){
      #pragma unroll
      for (int r=0;r<4;r++){
        float av = alphas[mt*16 + l4*4 + r];
        #pragma unroll
        for (int dt=0;dt<4;dt++) oacc[mt][dt][r] *= av;
      }
    }
    #pragma unroll
    for (int kp=0;kp<2;kp++){
      f16x8 pa[4];
      #pragma unroll
      for (int mt=0;mt<4;mt++) pa[mt] = *(f16x8*)&pb[mt*16 + l15][kp*32 + l4*8];
      #pragma unroll
      for (int dt=0;dt<4;dt++){
        #pragma unroll
        for (int mt=0;mt<4;mt++)
          oacc[mt][dt] = __builtin_amdgcn_mfma_f32_16x16x32_f16(pa[mt], vv[kp][dt], oacc[mt][dt], 0,0,0);
      }
    }
    __syncthreads();   // pbuf reads done + K prefetch drained (vmcnt 0) before next chunk
  }

  // ---- epilogue: publish 1/l, then H += O/l (fp16 RMW; each wave its d-quarter) ----
  if (l15 == 0){
    #pragma unroll
    for (int r=0;r<4;r++) linvs[mb + l4*4 + r] = 1.f / lrun[r];
  }
  __syncthreads();
  #pragma unroll
  for (int mt=0;mt<4;mt++){
    #pragma unroll
    for (int r=0;r<4;r++){
      float li = linvs[mt*16 + l4*4 + r];
      int t = t0 + mt*16 + l4*4 + r;
      _Float16* hp = &H[((size_t)b*TD + t)*DIM + dq];
      #pragma unroll
      for (int dt=0;dt<4;dt++){
        int idx = dt*16 + l15;
        hp[idx] = (_Float16)((float)hp[idx] + oacc[mt][dt][r] * li);
      }
    }
  }
}

// ---------- output projection as fp16 MFMA: out = Pb @ (Wph+Wpl)^T + bias ----------
__global__ __launch_bounds__(256) void k_proj_mfma(const _Float16* __restrict__ Hin,
    const _Float16* __restrict__ Wh, const _Float16* __restrict__ Wl,
    const float* __restrict__ bias, float* __restrict__ out)
{
  int blk = blockIdx.x;                 // 1024: 32 b x 32 t-tiles
  int b = blk >> 5;
  int t0 = (blk & 31) << 6;
  int tid = threadIdx.x;
  int wave = tid >> 6, lane = tid & 63;
  int l15 = lane & 15, l4 = lane >> 4;
  int mb = wave << 4;

  f16x8 ah[8];
  const _Float16* hrow = Hin + ((size_t)b*TD + t0 + mb + l15)*DIM;
  #pragma unroll
  for (int kc=0;kc<8;kc++) ah[kc] = *(const f16x8*)(hrow + kc*32 + l4*8);

  #pragma unroll
  for (int nt=0; nt<5; nt++){
    size_t wrow = (size_t)(nt*16 + l15)*256 + l4*8;
    f32x4 a = (f32x4){0.f,0.f,0.f,0.f};
    #pragma unroll
    for (int kc=0;kc<8;kc++){
      f16x8 bh = *(const f16x8*)(Wh + wrow + kc*32);
      f16x8 bl = *(const f16x8*)(Wl + wrow + kc*32);
      a = __builtin_amdgcn_mfma_f32_16x16x32_f16(ah[kc], bh, a, 0,0,0);
      a = __builtin_amdgcn_mfma_f32_16x16x32_f16(ah[kc], bl, a, 0,0,0);
    }
    int n = nt*16 + l15;
    float bv = bias[n];
    #pragma unroll
    for (int r=0;r<4;r++){
      int t = t0 + mb + l4*4 + r;
      out[((size_t)b*TD + t)*INDIM + n] = a[r] + bv;
    }
  }
}

extern "C" void kernel_launch(void* const* d_in, const int* in_sizes, int n_in,
                              void* d_out, int out_size, void* d_ws, size_t ws_size,
                              hipStream_t stream) {
  const float* enc   = (const float*)d_in[0];
  const float* emb   = (const float*)d_in[1];
  const float* mel   = (const float*)d_in[2];
  const float* W_lin = (const float*)d_in[3];
  const float* b_lin = (const float*)d_in[4];
  const float* w0    = (const float*)d_in[5];
  const float* b0    = (const float*)d_in[6];
  const float* w1    = (const float*)d_in[7];
  const float* b1    = (const float*)d_in[8];
  const float* Wq    = (const float*)d_in[9];
  const float* bq    = (const float*)d_in[10];
  const float* Wp    = (const float*)d_in[11];
  const float* bp    = (const float*)d_in[12];
  float* out = (float*)d_out;

  const size_t NTOK = (size_t)BB*TD*DIM;           // 16.78M
  const size_t NE   = (size_t)BB*TE*DIM;           // 8.39M
  _Float16* Xb  = (_Float16*)d_ws;
  _Float16* H   = Xb + NTOK;                       // fp16 end-to-end now
  _Float16* Wf0 = H + NTOK;
  _Float16* Wf1 = Wf0 + (size_t)512*1280;
  _Float16* Wqh = Wf1 + (size_t)512*1280;
  _Float16* Wql = Wqh + 65536;
  _Float16* Wlh = Wql + 65536;                     // 256*96
  _Float16* Wll = Wlh + 24576;
  _Float16* Wph = Wll + 24576;                     // 80*256
  _Float16* Wpl = Wph + 20480;
  _Float16* Eh  = Xb;                              // after conv0 consumes Xb
  _Float16* EVt = Xb + NE;
  _Float16* Pb  = Xb;                              // after attn consumes Eh/EVt

  k_wprep    <<<2560, 256, 0, stream>>>(w0, Wf0);
  k_wprep    <<<2560, 256, 0, stream>>>(w1, Wf1);
  k_qwprep   <<<256,  256, 0, stream>>>(Wq, Wqh, Wql);
  k_lwprep   <<<96,   256, 0, stream>>>(W_lin, Wlh, Wll);
  k_pwprep   <<<80,   256, 0, stream>>>(Wp, Wph, Wpl);
  k_lin_mfma <<<1024, 256, 0, stream>>>(mel, Wlh, Wll, b_lin, Xb);
  k_conv_mfma<0,0><<<4096, 256, 0, stream>>>(Xb, Wf0, b0, H);
  k_eprep    <<<2048, 256, 0, stream>>>(enc, emb, Eh, EVt);
  k_attn     <<<1024, 256, 0, stream>>>(H, Wqh, Wql, bq, Eh, EVt);
  k_conv_mfma<0,0><<<4096, 256, 0, stream>>>(H, Wf1, b1, Pb);
  k_proj_mfma<<<1024, 256, 0, stream>>>(Pb, Wph, Wpl, bp, out);
}